// Round 1
// baseline (1591.428 us; speedup 1.0000x reference)
//
#include <hip/hip_runtime.h>
#include <math.h>

// FlashAttention forward, faithful to the reference's blockwise recurrence
// INCLUDING its e_ij = exp(m_ij - m_new) bug (per-128-key-block max factor).
// fp32 baseline: CDNA4 has no fp32 MFMA, so this is a vector-ALU kernel.
//
// Shapes: (b=2, h=16, s=2048, d=128) fp32. B_C = 128 (semantic, fixed).
// Recurrence (U = l*O unnormalized):
//   U <- e_i*U + e_ij*(P@V),  l <- e_i*l + rowsum(P),  m <- max(m, m_ij)
//   final O = U / l.
// Blocks with j0 > q are exact no-ops -> q-tile t processes blocks 0..t.

#define NT   256      // threads per block (4 waves)
#define D    128      // head dim
#define BC   128      // key block (semantic)
#define BR   128      // query rows per workgroup
#define SEQQ 2048     // sequence length
#define LSTR 132      // fp32 LDS row stride for Qs/Ps (pad: 132 % 32 = 4)
#define KSTR 36       // K d-quarter tile stride: [128 k][36]
#define VSTR 132      // V k-quarter tile stride: [32 k][132]
#define FA_SCALE 0.08838834764831843f   // 1/sqrt(128)

// Prefetch one K d-quarter (32 of 128 d-cols, all 128 keys) into registers.
__device__ __forceinline__ void load_Kq(const float* __restrict__ Kb, int kb, int q,
                                        int tid, float4 pf[4]) {
#pragma unroll
  for (int i = 0; i < 4; ++i) {
    int f = tid + i * NT;          // 1024 float4 = 128 x 32 floats
    int kr = f >> 3, c4 = f & 7;   // 8 float4 per key row (coalesced 128B rows)
    pf[i] = *(const float4*)(Kb + (size_t)(kb * BC + kr) * D + q * 32 + c4 * 4);
  }
}

// Prefetch one V k-quarter (32 keys, all 128 d-cols) into registers.
__device__ __forceinline__ void load_Vq(const float* __restrict__ Vb, int kb, int q,
                                        int tid, float4 pf[4]) {
#pragma unroll
  for (int i = 0; i < 4; ++i) {
    int f = tid + i * NT;          // 1024 float4 = 32 x 128 floats
    int kr = f >> 5, c4 = f & 31;  // 32 float4 per key row (coalesced)
    pf[i] = *(const float4*)(Vb + (size_t)(kb * BC + q * 32 + kr) * D + c4 * 4);
  }
}

__global__ __launch_bounds__(NT, 1) void fa_fwd_fp32(
    const float* __restrict__ Q, const float* __restrict__ K,
    const float* __restrict__ V, float* __restrict__ O) {
  const int qt = blockIdx.x;   // q-tile: 0..15
  const int bh = blockIdx.y;   // batch*head: 0..31
  const size_t base = (size_t)bh * SEQQ * D;
  const float* Qb = Q + base;
  const float* Kb = K + base;
  const float* Vb = V + base;
  float* Ob = O + base;

  const int tid = threadIdx.x;
  const int tc = tid & 15;     // k/d column group (16)
  const int tr = tid >> 4;     // q row group (16)

  __shared__ float Qs[BR][LSTR];        // 67584 B, staged once
  __shared__ float Ps[BR][LSTR];        // 67584 B, S then P (e_ij folded in)
  __shared__ float KVs[128 * KSTR];     // 18432 B, K d-quarters / V k-quarters
  __shared__ float m_s[BR], l_s[BR], ei_s[BR], eij_s[BR];
  __shared__ float pm2[BR][2], psum[BR][2];
  // total LDS = 157696 B <= 163840 -> 1 block/CU

  // ---- stage Q tile (once), init state ----
#pragma unroll
  for (int i = 0; i < 16; ++i) {
    int f = tid + i * NT;
    int r = f >> 5, c4 = f & 31;
    *(float4*)&Qs[r][c4 * 4] =
        *(const float4*)(Qb + (size_t)(qt * BR + r) * D + c4 * 4);
  }
  if (tid < BR) { m_s[tid] = -INFINITY; l_s[tid] = 0.f; }

  float u[8][8];                 // U accumulator: rows tr+16i, cols tc+16j
#pragma unroll
  for (int i = 0; i < 8; ++i)
#pragma unroll
    for (int j = 0; j < 8; ++j) u[i][j] = 0.f;

  const int jmax = qt;           // causal: blocks 0..qt
  float4 pf[4];
  load_Kq(Kb, 0, 0, tid, pf);    // prefetch pipeline head

  __syncthreads();

  for (int kb = 0; kb <= jmax; ++kb) {
    // ================= S = Q @ K^T (accumulate over 4 d-quarters) =========
    float s[8][8];
#pragma unroll
    for (int i = 0; i < 8; ++i)
#pragma unroll
      for (int j = 0; j < 8; ++j) s[i][j] = 0.f;

    for (int q = 0; q < 4; ++q) {
      __syncthreads();           // KVs free (prev phase's readers done)
#pragma unroll
      for (int i = 0; i < 4; ++i) {       // regs -> LDS (vmcnt wait is implicit)
        int f = tid + i * NT;
        int kr = f >> 3, c4 = f & 7;
        *(float4*)&KVs[kr * KSTR + c4 * 4] = pf[i];
      }
      if (q < 3) load_Kq(Kb, kb, q + 1, tid, pf);   // prefetch next phase
      else       load_Vq(Vb, kb, 0, tid, pf);
      __syncthreads();
#pragma unroll
      for (int d4 = 0; d4 < 8; ++d4) {    // 4-d chunks within the quarter
        float4 a[8], b[8];
#pragma unroll
        for (int i = 0; i < 8; ++i)
          a[i] = *(const float4*)&Qs[tr + 16 * i][q * 32 + d4 * 4];
#pragma unroll
        for (int j = 0; j < 8; ++j)
          b[j] = *(const float4*)&KVs[(tc + 16 * j) * KSTR + d4 * 4];
#pragma unroll
        for (int i = 0; i < 8; ++i)
#pragma unroll
          for (int j = 0; j < 8; ++j) {
            s[i][j] = fmaf(a[i].x, b[j].x, s[i][j]);
            s[i][j] = fmaf(a[i].y, b[j].y, s[i][j]);
            s[i][j] = fmaf(a[i].z, b[j].z, s[i][j]);
            s[i][j] = fmaf(a[i].w, b[j].w, s[i][j]);
          }
      }
    }

    // ---- write S -> Ps with scale + causal mask ----
#pragma unroll
    for (int i = 0; i < 8; ++i) {
      int qg = qt * BR + tr + 16 * i;
#pragma unroll
      for (int j = 0; j < 8; ++j) {
        int kg = kb * BC + tc + 16 * j;
        float v = s[i][j] * FA_SCALE;
        Ps[tr + 16 * i][tc + 16 * j] = (kg > qg) ? -INFINITY : v;
      }
    }
    __syncthreads();

    // ---- softmax block update (exact reference semantics, incl. e_ij) ----
    {  // SM1: per-half row max
      int r = tid >> 1, h = tid & 1;
      float mx = -INFINITY;
#pragma unroll
      for (int c4 = 0; c4 < 16; ++c4) {
        float4 v = *(const float4*)&Ps[r][h * 64 + c4 * 4];
        mx = fmaxf(mx, fmaxf(fmaxf(v.x, v.y), fmaxf(v.z, v.w)));
      }
      pm2[r][h] = mx;
    }
    __syncthreads();
    if (tid < BR) {  // SM2: m_new, e_i, e_ij
      float mij = fmaxf(pm2[tid][0], pm2[tid][1]);   // finite (diag always has k<=q)
      float mo = m_s[tid];
      float mn = fmaxf(mo, mij);
      m_s[tid] = mn;
      ei_s[tid]  = __expf(mo - mn);    // exp(-inf)=0 on first block
      eij_s[tid] = __expf(mij - mn);   // the reference's bug factor
    }
    __syncthreads();
    {  // SM3: P = exp(S - m_new); plain sum for l; store P*e_ij for PV
      int r = tid >> 1, h = tid & 1;
      float mn = m_s[r], ej = eij_s[r];
      float sm = 0.f;
#pragma unroll
      for (int c4 = 0; c4 < 16; ++c4) {
        float4 v = *(float4*)&Ps[r][h * 64 + c4 * 4];
        v.x = __expf(v.x - mn); v.y = __expf(v.y - mn);
        v.z = __expf(v.z - mn); v.w = __expf(v.w - mn);
        sm += v.x + v.y + v.z + v.w;
        v.x *= ej; v.y *= ej; v.z *= ej; v.w *= ej;
        *(float4*)&Ps[r][h * 64 + c4 * 4] = v;
      }
      psum[r][h] = sm;
    }
    __syncthreads();
    if (tid < BR)  // SM4: l <- e_i*l + rowsum(P)
      l_s[tid] = ei_s[tid] * l_s[tid] + psum[tid][0] + psum[tid][1];

    // U <- e_i * U   (ei_s stable: written SM2, barriered at SM3)
#pragma unroll
    for (int i = 0; i < 8; ++i) {
      float ei = ei_s[tr + 16 * i];
#pragma unroll
      for (int j = 0; j < 8; ++j) u[i][j] *= ei;
    }

    // ================= U += (e_ij*P) @ V (4 k-quarters) ===================
    for (int qk = 0; qk < 4; ++qk) {
      __syncthreads();           // KVs free
#pragma unroll
      for (int i = 0; i < 4; ++i) {
        int f = tid + i * NT;
        int kr = f >> 5, c4 = f & 31;
        *(float4*)&KVs[kr * VSTR + c4 * 4] = pf[i];
      }
      if (qk < 3)          load_Vq(Vb, kb, qk + 1, tid, pf);
      else if (kb < jmax)  load_Kq(Kb, kb + 1, 0, tid, pf);
      __syncthreads();
#pragma unroll
      for (int k4 = 0; k4 < 8; ++k4) {   // 4-k chunks within the quarter
        float4 a[8];
        float b[4][8];
#pragma unroll
        for (int i = 0; i < 8; ++i)
          a[i] = *(const float4*)&Ps[tr + 16 * i][qk * 32 + k4 * 4];
#pragma unroll
        for (int kk = 0; kk < 4; ++kk)
#pragma unroll
          for (int j = 0; j < 8; ++j)
            b[kk][j] = KVs[(k4 * 4 + kk) * VSTR + tc + 16 * j];
#pragma unroll
        for (int i = 0; i < 8; ++i)
#pragma unroll
          for (int j = 0; j < 8; ++j) {
            u[i][j] = fmaf(a[i].x, b[0][j], u[i][j]);
            u[i][j] = fmaf(a[i].y, b[1][j], u[i][j]);
            u[i][j] = fmaf(a[i].z, b[2][j], u[i][j]);
            u[i][j] = fmaf(a[i].w, b[3][j], u[i][j]);
          }
      }
    }
  }

  // ---- epilogue: O = U / l ----
#pragma unroll
  for (int i = 0; i < 8; ++i) {
    float rl = 1.0f / l_s[tr + 16 * i];
    size_t row = (size_t)(qt * BR + tr + 16 * i) * D;
#pragma unroll
    for (int j = 0; j < 8; ++j)
      Ob[row + tc + 16 * j] = u[i][j] * rl;
  }
}

extern "C" void kernel_launch(void* const* d_in, const int* in_sizes, int n_in,
                              void* d_out, int out_size, void* d_ws, size_t ws_size,
                              hipStream_t stream) {
  const float* Q = (const float*)d_in[0];
  const float* K = (const float*)d_in[1];
  const float* V = (const float*)d_in[2];
  float* O = (float*)d_out;
  (void)in_sizes; (void)n_in; (void)out_size; (void)d_ws; (void)ws_size;

  dim3 grid(SEQQ / BR, 32);   // 16 q-tiles x (b*h = 32)
  dim3 block(NT);
  hipLaunchKernelGGL(fa_fwd_fp32, grid, block, 0, stream, Q, K, V, O);
}

// Round 2
// 370.424 us; speedup vs baseline: 4.2962x; 4.2962x over previous
//
#include <hip/hip_runtime.h>
#include <math.h>

// FlashAttention fwd, faithful to reference blockwise recurrence INCLUDING the
// e_ij = exp(m_ij - m_new) per-128-block bug. f16 MFMA (16x16x32, fp32 accum).
// (b,h,s,d) = (2,16,2048,128) fp32 in/out. B_C = 128 (semantic).
//
// Pre-pass: Kh = f16(K) [bh][s][d]; Vt = f16(V^T) [bh][d][s]  (both in d_ws,
// needs ws_size >= 32 MB). Main kernel: per (q-tile 128, bh): 8 waves (2x4),
// each wave owns 64 q-rows x 32 cols. Q in regs; K double-buffered LDS; V,P
// single LDS tiles. All LDS f16 tiles XOR-swizzled (byte ^= (row&7)<<4);
// K/V staged with global_load_lds(16B) using inverse-swizzled global source.

using f16   = _Float16;
using f16x8 = __attribute__((ext_vector_type(8))) _Float16;
using f16x4 = __attribute__((ext_vector_type(4))) _Float16;
using f32x4 = __attribute__((ext_vector_type(4))) float;

#define SEQ   2048
#define DK    128
#define NQT   16
#define FA_SCALE 0.08838834764831843f   // 1/sqrt(128)

// ---------------- pre-pass 1: K fp32 -> f16 (same layout) ----------------
__global__ __launch_bounds__(256) void cvt_k(const float* __restrict__ K,
                                             f16* __restrict__ Kh) {
  int i = blockIdx.x * 256 + threadIdx.x;     // one 8-elem unit per thread
  const float4* src = (const float4*)K;
  float4 a = src[2 * i], b = src[2 * i + 1];
  f16x8 h;
  h[0] = (f16)a.x; h[1] = (f16)a.y; h[2] = (f16)a.z; h[3] = (f16)a.w;
  h[4] = (f16)b.x; h[5] = (f16)b.y; h[6] = (f16)b.z; h[7] = (f16)b.w;
  ((f16x8*)Kh)[i] = h;
}

// ------------- pre-pass 2: V fp32 [bh][s][d] -> Vt f16 [bh][d][s] --------
__global__ __launch_bounds__(256) void trans_v(const float* __restrict__ V,
                                               f16* __restrict__ Vt) {
  __shared__ float Vsh[128 * 132];            // +4 pad: conflict-free col reads
  int st = blockIdx.x, bh = blockIdx.y, tid = threadIdx.x;
  const float* src = V + ((size_t)bh * SEQ + st * 128) * DK;
#pragma unroll
  for (int i = 0; i < 16; ++i) {
    int f = tid + i * 256;
    int k = f >> 5, c = f & 31;
    *(float4*)&Vsh[k * 132 + c * 4] = *(const float4*)(src + k * DK + c * 4);
  }
  __syncthreads();
  int d = tid >> 1, hf = tid & 1;             // 2 threads per output row d
  f16* dst = Vt + (size_t)bh * DK * SEQ + (size_t)d * SEQ + st * 128 + hf * 64;
#pragma unroll
  for (int kk = 0; kk < 64; kk += 4) {
    f16x4 h;
    h[0] = (f16)Vsh[(hf * 64 + kk + 0) * 132 + d];
    h[1] = (f16)Vsh[(hf * 64 + kk + 1) * 132 + d];
    h[2] = (f16)Vsh[(hf * 64 + kk + 2) * 132 + d];
    h[3] = (f16)Vsh[(hf * 64 + kk + 3) * 132 + d];
    *(f16x4*)(dst + kk) = h;
  }
}

// ---------------- main kernel ----------------
__device__ __forceinline__ void gl_lds16(const void* g, void* l) {
  __builtin_amdgcn_global_load_lds(
      (const __attribute__((address_space(1))) unsigned int*)g,
      (__attribute__((address_space(3))) unsigned int*)l, 16, 0, 0);
}

// Stage a 128x(256B) tile (32 KB) into linear LDS; global source pre-swizzled
// so that swizzled reads (byte ^ ((row&7)<<4)) see the logical layout.
__device__ __forceinline__ void stage32k(const char* gbase, int gstride,
                                         char* lds, int w, int lg, int ll) {
#pragma unroll
  for (int i = 0; i < 4; ++i) {
    int t = w * 4 + i;                 // 32 x 1KB chunks, 4 per wave
    int row = t * 4 + lg;              // 4 rows (256B) per chunk
    int blog = (ll * 16) ^ ((row & 7) << 4);
    gl_lds16(gbase + (size_t)row * gstride + blog, lds + t * 1024);
  }
}

__global__ __launch_bounds__(512, 2) void fa_fwd_f16(
    const float* __restrict__ Q, const f16* __restrict__ Kh,
    const f16* __restrict__ Vt, float* __restrict__ O) {
  const int qt = (NQT - 1) - blockIdx.x;   // biggest causal tiles first
  const int bh = blockIdx.y;
  const int tid  = threadIdx.x;
  const int lane = tid & 63;
  const int w  = tid >> 6;   // wave 0..7
  const int wr = w >> 2;     // q-half 0..1  (64 rows each)
  const int wc = w & 3;      // col-quarter 0..3 (32 cols each)
  const int lg = lane >> 4;  // k-group 0..3
  const int ll = lane & 15;
  const int swz = (ll & 7) << 4;   // row&7 == ll&7 for all frag-read rows

  __shared__ __align__(16) f16 Ks[2][128 * 128];  // 2 x 32 KB (double buf)
  __shared__ __align__(16) f16 Vs[128 * 128];     // 32 KB  (V^T block: [d][k])
  __shared__ __align__(16) f16 Ps[128 * 128];     // 32 KB  (P, e_ij folded)
  __shared__ float m_s[128], l_s[128], ei_s[128], eij_s[128];
  __shared__ float pmax[128][4], psum[128][4];    // per-wc partials
  // total 137,216 B -> 1 block/CU, 8 waves = 2 waves/SIMD

  const float* QB = Q + (size_t)bh * SEQ * DK;
  const char*  KB = (const char*)(Kh + (size_t)bh * SEQ * DK);
  const char*  VB = (const char*)(Vt + (size_t)bh * DK * SEQ);
  float*       OB = O + (size_t)bh * SEQ * DK;

  // ---- Q fragments in registers: A[row=ll][k-chunk lg*8], f16 ----
  f16x8 qf[4][4];
#pragma unroll
  for (int mi = 0; mi < 4; ++mi)
#pragma unroll
    for (int c = 0; c < 4; ++c) {
      const float* p =
          QB + (size_t)(qt * 128 + wr * 64 + mi * 16 + ll) * DK + c * 32 + lg * 8;
      float4 a = *(const float4*)p, b = *(const float4*)(p + 4);
      f16x8 h;
      h[0] = (f16)a.x; h[1] = (f16)a.y; h[2] = (f16)a.z; h[3] = (f16)a.w;
      h[4] = (f16)b.x; h[5] = (f16)b.y; h[6] = (f16)b.z; h[7] = (f16)b.w;
      qf[mi][c] = h;
    }

  f32x4 u[4][2];   // U accumulator (rows lg*4+j, cols wc*32+n*16+ll)
#pragma unroll
  for (int mi = 0; mi < 4; ++mi) { u[mi][0] = 0; u[mi][1] = 0; }

  if (tid < 128) { m_s[tid] = -INFINITY; l_s[tid] = 0.f; }

  stage32k(KB, 256, (char*)&Ks[0][0], w, lg, ll);   // K block 0
  stage32k(VB, 4096, (char*)&Vs[0], w, lg, ll);     // V block 0 (Vt rows)
  __syncthreads();

  for (int kb = 0; kb <= qt; ++kb) {
    const int cur = kb & 1;
    if (kb < qt)   // prefetch next K block into other buffer
      stage32k(KB + (size_t)(kb + 1) * 32768, 256, (char*)&Ks[cur ^ 1][0], w, lg, ll);

    // ================= S = Q K^T =================
    f32x4 s[4][2];
#pragma unroll
    for (int mi = 0; mi < 4; ++mi) { s[mi][0] = 0; s[mi][1] = 0; }
    const char* Kc = (const char*)&Ks[cur][0];
#pragma unroll
    for (int c = 0; c < 4; ++c) {
      const int boff = (c * 64 + lg * 16) ^ swz;
      f16x8 k0 = *(const f16x8*)(Kc + (wc * 32      + ll) * 256 + boff);
      f16x8 k1 = *(const f16x8*)(Kc + (wc * 32 + 16 + ll) * 256 + boff);
#pragma unroll
      for (int mi = 0; mi < 4; ++mi) {
        s[mi][0] = __builtin_amdgcn_mfma_f32_16x16x32_f16(qf[mi][c], k0, s[mi][0], 0, 0, 0);
        s[mi][1] = __builtin_amdgcn_mfma_f32_16x16x32_f16(qf[mi][c], k1, s[mi][1], 0, 0, 0);
      }
    }

    // ---- scale + causal mask (diag block only) + per-row partial max ----
    const bool diag = (kb == qt);
    float rmax[4][4];
#pragma unroll
    for (int mi = 0; mi < 4; ++mi)
#pragma unroll
      for (int j = 0; j < 4; ++j) rmax[mi][j] = -INFINITY;
#pragma unroll
    for (int mi = 0; mi < 4; ++mi)
#pragma unroll
      for (int n = 0; n < 2; ++n)
#pragma unroll
        for (int j = 0; j < 4; ++j) {
          float v = s[mi][n][j] * FA_SCALE;
          if (diag) {
            int lr = wr * 64 + mi * 16 + lg * 4 + j;
            int lc = wc * 32 + n * 16 + ll;
            if (lc > lr) v = -INFINITY;
          }
          s[mi][n][j] = v;
          rmax[mi][j] = fmaxf(rmax[mi][j], v);
        }
#pragma unroll
    for (int mk = 1; mk < 16; mk <<= 1)
#pragma unroll
      for (int mi = 0; mi < 4; ++mi)
#pragma unroll
        for (int j = 0; j < 4; ++j)
          rmax[mi][j] = fmaxf(rmax[mi][j], __shfl_xor(rmax[mi][j], mk));
#pragma unroll
    for (int mi = 0; mi < 4; ++mi)    // one lane per (group,row) writes
#pragma unroll
      for (int j = 0; j < 4; ++j)
        if (ll == mi * 4 + j) pmax[wr * 64 + mi * 16 + lg * 4 + j][wc] = rmax[mi][j];
    __syncthreads();

    if (tid < 128) {   // combine 4 wc partials; m/e_i/e_ij update
      float mij = fmaxf(fmaxf(pmax[tid][0], pmax[tid][1]),
                        fmaxf(pmax[tid][2], pmax[tid][3]));
      float mo = m_s[tid];
      float mnv = fmaxf(mo, mij);
      m_s[tid] = mnv;
      ei_s[tid]  = __expf(mo - mnv);    // exp(-inf)=0 on first block
      eij_s[tid] = __expf(mij - mnv);   // the reference's bug factor
    }
    __syncthreads();

    // ---- P = exp(S - m_new); partial sums; U rescale; Ps (e_ij*P) write ----
    float mn[4][4], ei[4][4], ej[4][4], pp[4][4];
#pragma unroll
    for (int mi = 0; mi < 4; ++mi)
#pragma unroll
      for (int j = 0; j < 4; ++j) {
        int r = wr * 64 + mi * 16 + lg * 4 + j;
        mn[mi][j] = m_s[r]; ei[mi][j] = ei_s[r]; ej[mi][j] = eij_s[r];
        pp[mi][j] = 0.f;
      }
    char* Pc = (char*)&Ps[0];
#pragma unroll
    for (int mi = 0; mi < 4; ++mi)
#pragma unroll
      for (int n = 0; n < 2; ++n)
#pragma unroll
        for (int j = 0; j < 4; ++j) {
          float p = __expf(s[mi][n][j] - mn[mi][j]);
          pp[mi][j] += p;                       // plain P-sum for l
          int row = wr * 64 + mi * 16 + lg * 4 + j;
          int col = wc * 32 + n * 16 + ll;
          *(f16*)(Pc + row * 256 + ((col * 2) ^ ((row & 7) << 4))) =
              (f16)(p * ej[mi][j]);             // fold e_ij for PV
        }
#pragma unroll
    for (int mi = 0; mi < 4; ++mi)              // U <- e_i * U
#pragma unroll
      for (int n = 0; n < 2; ++n)
#pragma unroll
        for (int j = 0; j < 4; ++j) u[mi][n][j] *= ei[mi][j];
#pragma unroll
    for (int mk = 1; mk < 16; mk <<= 1)
#pragma unroll
      for (int mi = 0; mi < 4; ++mi)
#pragma unroll
        for (int j = 0; j < 4; ++j) pp[mi][j] += __shfl_xor(pp[mi][j], mk);
#pragma unroll
    for (int mi = 0; mi < 4; ++mi)
#pragma unroll
      for (int j = 0; j < 4; ++j)
        if (ll == mi * 4 + j) psum[wr * 64 + mi * 16 + lg * 4 + j][wc] = pp[mi][j];
    __syncthreads();

    if (tid < 128)   // l <- e_i*l + rowsum(P)
      l_s[tid] = ei_s[tid] * l_s[tid] +
                 psum[tid][0] + psum[tid][1] + psum[tid][2] + psum[tid][3];

    // ================= U += (e_ij P) V =================
    const char* Vc = (const char*)&Vs[0];
#pragma unroll
    for (int c = 0; c < 4; ++c) {
      const int boff = (c * 64 + lg * 16) ^ swz;
      f16x8 pa0 = *(const f16x8*)(Pc + (wr * 64      + ll) * 256 + boff);
      f16x8 pa1 = *(const f16x8*)(Pc + (wr * 64 + 16 + ll) * 256 + boff);
      f16x8 pa2 = *(const f16x8*)(Pc + (wr * 64 + 32 + ll) * 256 + boff);
      f16x8 pa3 = *(const f16x8*)(Pc + (wr * 64 + 48 + ll) * 256 + boff);
      f16x8 v0  = *(const f16x8*)(Vc + (wc * 32      + ll) * 256 + boff);
      f16x8 v1  = *(const f16x8*)(Vc + (wc * 32 + 16 + ll) * 256 + boff);
      u[0][0] = __builtin_amdgcn_mfma_f32_16x16x32_f16(pa0, v0, u[0][0], 0, 0, 0);
      u[0][1] = __builtin_amdgcn_mfma_f32_16x16x32_f16(pa0, v1, u[0][1], 0, 0, 0);
      u[1][0] = __builtin_amdgcn_mfma_f32_16x16x32_f16(pa1, v0, u[1][0], 0, 0, 0);
      u[1][1] = __builtin_amdgcn_mfma_f32_16x16x32_f16(pa1, v1, u[1][1], 0, 0, 0);
      u[2][0] = __builtin_amdgcn_mfma_f32_16x16x32_f16(pa2, v0, u[2][0], 0, 0, 0);
      u[2][1] = __builtin_amdgcn_mfma_f32_16x16x32_f16(pa2, v1, u[2][1], 0, 0, 0);
      u[3][0] = __builtin_amdgcn_mfma_f32_16x16x32_f16(pa3, v0, u[3][0], 0, 0, 0);
      u[3][1] = __builtin_amdgcn_mfma_f32_16x16x32_f16(pa3, v1, u[3][1], 0, 0, 0);
    }
    __syncthreads();   // PV reads done; l_s final for this kb
    if (kb < qt)       // stage next V block (drained at next iter's barrier)
      stage32k(VB + (size_t)(kb + 1) * 256, 4096, (char*)&Vs[0], w, lg, ll);
  }

  // ---- epilogue: O = U / l ----
#pragma unroll
  for (int mi = 0; mi < 4; ++mi)
#pragma unroll
    for (int j = 0; j < 4; ++j) {
      int r = wr * 64 + mi * 16 + lg * 4 + j;
      float rl = 1.0f / l_s[r];
      size_t row = (size_t)(qt * 128 + r) * DK;
      OB[row + wc * 32      + ll] = u[mi][0][j] * rl;
      OB[row + wc * 32 + 16 + ll] = u[mi][1][j] * rl;
    }
}

extern "C" void kernel_launch(void* const* d_in, const int* in_sizes, int n_in,
                              void* d_out, int out_size, void* d_ws, size_t ws_size,
                              hipStream_t stream) {
  const float* Q = (const float*)d_in[0];
  const float* K = (const float*)d_in[1];
  const float* V = (const float*)d_in[2];
  float* O = (float*)d_out;
  (void)in_sizes; (void)n_in; (void)out_size; (void)ws_size;

  f16* Kh = (f16*)d_ws;                              // 16 MB
  f16* Vt = (f16*)((char*)d_ws + 16777216);          // 16 MB (needs ws >= 32MB)

  cvt_k<<<4096, 256, 0, stream>>>(K, Kh);
  trans_v<<<dim3(16, 32), 256, 0, stream>>>(V, Vt);
  fa_fwd_f16<<<dim3(16, 32), 512, 0, stream>>>(Q, Kh, Vt, O);
}

// Round 3
// 194.604 us; speedup vs baseline: 8.1778x; 1.9035x over previous
//
#include <hip/hip_runtime.h>
#include <math.h>

// FlashAttention fwd, faithful to reference blockwise recurrence INCLUDING the
// e_ij = exp(m_ij - m_new) per-128-block bug. f16 MFMA 16x16x32, fp32 accum.
// (b,h,s,d) = (2,16,2048,128) fp32 in/out. B_C = 128 (semantic).
//
// R3 structure: swapped QK^T (mfma(K,Q)) -> each lane owns one q-row's S
// values -> softmax fully in registers (no LDS partials, no serial phases).
// PV uses a k-PERMUTED V layout (built in pre-pass) so the lane's P values
// already sit in A-fragment slot order: zero cross-lane traffic for P.
// One barrier per k-block iteration; K and V double-buffered (128 KB LDS).
//
// Pre-pass: Kh = f16(K) [bh][s][d]; Vtp = f16 permuted V^T [bh][d][slot]
// where within each 128-key block, slot(k16*16+b) = (k16>>1)*32 + (b>>2)*8
// + (k16&1)*4 + (b&3)  (bijective). Then PV B-frag reads are contiguous 16B.

using f16   = _Float16;
using f16x8 = __attribute__((ext_vector_type(8))) _Float16;
using f32x4 = __attribute__((ext_vector_type(4))) float;

#define SEQ 2048
#define DK  128
#define FA_SCALE 0.08838834764831843f   // 1/sqrt(128)

// ---------------- pre-pass 1: K fp32 -> f16 (same layout) ----------------
__global__ __launch_bounds__(256) void cvt_k(const float* __restrict__ K,
                                             f16* __restrict__ Kh) {
  int i = blockIdx.x * 256 + threadIdx.x;
  const float4* src = (const float4*)K;
  float4 a = src[2 * i], b = src[2 * i + 1];
  f16x8 h;
  h[0] = (f16)a.x; h[1] = (f16)a.y; h[2] = (f16)a.z; h[3] = (f16)a.w;
  h[4] = (f16)b.x; h[5] = (f16)b.y; h[6] = (f16)b.z; h[7] = (f16)b.w;
  ((f16x8*)Kh)[i] = h;
}

// ---- pre-pass 2: V fp32 [bh][s][d] -> Vtp f16 [bh][d][block*128 + slot] ----
// slot permutation within each 128-key block as documented above.
__global__ __launch_bounds__(256) void trans_v(const float* __restrict__ V,
                                               f16* __restrict__ Vtp) {
  __shared__ float Vsh[128][132];          // +4 pad: conflict-free col reads
  int st = blockIdx.x, bh = blockIdx.y, tid = threadIdx.x;
  const float* src = V + ((size_t)bh * SEQ + st * 128) * DK;
#pragma unroll
  for (int i = 0; i < 16; ++i) {
    int f = tid + i * 256;
    int k = f >> 5, c = f & 31;
    *(float4*)&Vsh[k][c * 4] = *(const float4*)(src + k * DK + c * 4);
  }
  __syncthreads();
  int d = tid >> 1, hf = tid & 1;          // 2 threads per output row d
  f16* dst = Vtp + (size_t)bh * DK * SEQ + (size_t)d * SEQ + st * 128 + hf * 64;
#pragma unroll
  for (int i = 0; i < 8; ++i) {            // 8 aligned slot-runs of 8
    int s0 = hf * 64 + i * 8;
    int c  = s0 >> 5;
    int lgs = (s0 >> 3) & 3;
    f16x8 hv;
#pragma unroll
    for (int o = 0; o < 8; ++o) {
      int k = (2 * c + (o >> 2)) * 16 + lgs * 4 + (o & 3);  // phys k for slot
      hv[o] = (f16)Vsh[k][d];
    }
    *(f16x8*)(dst + i * 8) = hv;           // coalesced 16B stores
  }
}

// ---------------- main kernel helpers ----------------
__device__ __forceinline__ void gl_lds16(const void* g, void* l) {
  __builtin_amdgcn_global_load_lds(
      (const __attribute__((address_space(1))) unsigned int*)g,
      (__attribute__((address_space(3))) unsigned int*)l, 16, 0, 0);
}

// Stage a 128-row x 256B tile (32 KB) into LDS; global source pre-swizzled so
// swizzled reads (byte ^ ((row&7)<<4)) see the logical layout. (Proven in R2.)
__device__ __forceinline__ void stage32k(const char* gbase, size_t gstride,
                                         char* lds, int w, int lg, int ll) {
#pragma unroll
  for (int i = 0; i < 4; ++i) {
    int t = w * 4 + i;                 // 32 x 1KB chunks, 4 per wave
    int row = t * 4 + lg;              // lane lg -> row within chunk
    int blog = (ll * 16) ^ ((row & 7) << 4);
    gl_lds16(gbase + (size_t)row * gstride + blog, lds + t * 1024);
  }
}

__global__ __launch_bounds__(512, 2) void fa_fwd_f16(
    const float* __restrict__ Q, const f16* __restrict__ Kh,
    const f16* __restrict__ Vtp, float* __restrict__ O) {
  const int bh = blockIdx.x;
  const int qt = 15 - blockIdx.y;          // big causal tiles dispatch first
  const int tid  = threadIdx.x;
  const int lane = tid & 63;
  const int w  = tid >> 6;                 // wave 0..7: owns q-rows w*16..+15
  const int ll = lane & 15;
  const int lg = lane >> 4;
  const int swz = (ll & 7) << 4;

  __shared__ __align__(16) f16 Ks[2][128 * 128];   // 2 x 32 KB
  __shared__ __align__(16) f16 Vs[2][128 * 128];   // 2 x 32 KB (permuted V^T)
  // 131072 B total -> 1 block/CU, 8 waves (2/SIMD); no other LDS needed.

  const float* QB = Q + (size_t)bh * SEQ * DK;
  const char*  KB = (const char*)(Kh + (size_t)bh * SEQ * DK);
  const char*  VB = (const char*)(Vtp + (size_t)bh * DK * SEQ);
  float*       OB = O + (size_t)bh * SEQ * DK;

  const int qrow = qt * 128 + w * 16 + ll;   // this lane's q-row (QK side)

  // Q B-frag (regs): B[q=ll][d = dc*32 + lg*8 + o]
  f16x8 qf[4];
#pragma unroll
  for (int dc = 0; dc < 4; ++dc) {
    const float* p = QB + (size_t)qrow * DK + dc * 32 + lg * 8;
    float4 a = *(const float4*)p, b = *(const float4*)(p + 4);
    f16x8 h;
    h[0] = (f16)a.x; h[1] = (f16)a.y; h[2] = (f16)a.z; h[3] = (f16)a.w;
    h[4] = (f16)b.x; h[5] = (f16)b.y; h[6] = (f16)b.z; h[7] = (f16)b.w;
    qf[dc] = h;
  }

  f32x4 u[8];                 // U: rows lg*4+j (within wave), cols n*16+ll
#pragma unroll
  for (int n = 0; n < 8; ++n) u[n] = 0;
  float m = -INFINITY, lsum = 0.f;   // per-lane q-row state (4 synced copies)

  stage32k(KB, 256, (char*)&Ks[0][0], w, lg, ll);
  stage32k(VB, 4096, (char*)&Vs[0][0], w, lg, ll);
  __syncthreads();

  for (int kb = 0; kb <= qt; ++kb) {
    const int cur = kb & 1;
    if (kb < qt) {   // prefetch next block into other buffers (drained at barrier)
      stage32k(KB + (size_t)(kb + 1) * 32768, 256, (char*)&Ks[cur ^ 1][0], w, lg, ll);
      stage32k(VB + (size_t)(kb + 1) * 256, 4096, (char*)&Vs[cur ^ 1][0], w, lg, ll);
    }

    // ---- S^T = K Q^T : s[k16][r] = S[q=ll][k = k16*16 + lg*4 + r] ----
    f32x4 s[8];
#pragma unroll
    for (int k16 = 0; k16 < 8; ++k16) s[k16] = 0;
    const char* Kc = (const char*)&Ks[cur][0];
#pragma unroll
    for (int dc = 0; dc < 4; ++dc) {
      const int boff = (dc * 64 + lg * 16) ^ swz;
#pragma unroll
      for (int k16 = 0; k16 < 8; ++k16) {
        f16x8 kf = *(const f16x8*)(Kc + (k16 * 16 + ll) * 256 + boff);
        s[k16] = __builtin_amdgcn_mfma_f32_16x16x32_f16(kf, qf[dc], s[k16], 0, 0, 0);
      }
    }

    // ---- scale + causal mask (diag only) + in-register row max ----
    float mx = -INFINITY;
    if (kb == qt) {
      const int kbase = kb * 128;
#pragma unroll
      for (int k16 = 0; k16 < 8; ++k16)
#pragma unroll
        for (int r = 0; r < 4; ++r) {
          float v = s[k16][r] * FA_SCALE;
          if (kbase + k16 * 16 + lg * 4 + r > qrow) v = -INFINITY;
          s[k16][r] = v;
          mx = fmaxf(mx, v);
        }
    } else {
#pragma unroll
      for (int k16 = 0; k16 < 8; ++k16)
#pragma unroll
        for (int r = 0; r < 4; ++r) {
          float v = s[k16][r] * FA_SCALE;
          s[k16][r] = v;
          mx = fmaxf(mx, v);
        }
    }
    mx = fmaxf(mx, __shfl_xor(mx, 16));   // combine the 4 lg copies of row ll
    mx = fmaxf(mx, __shfl_xor(mx, 32));

    const float mn = fmaxf(m, mx);        // m_new
    const float ei = __expf(m - mn);      // exp(-inf)=0 on first block
    const float ej = __expf(mx - mn);     // the reference's e_ij bug factor
    m = mn;

    // ---- P = exp(S - m_new); plain row sum for l ----
    float ps = 0.f;
#pragma unroll
    for (int k16 = 0; k16 < 8; ++k16)
#pragma unroll
      for (int r = 0; r < 4; ++r) {
        float p = __expf(s[k16][r] - mn);
        s[k16][r] = p;
        ps += p;
      }
    ps += __shfl_xor(ps, 16);
    ps += __shfl_xor(ps, 32);
    lsum = ei * lsum + ps;

    // ---- pack PV A-frags in-register (e_ij folded); slot order matches
    //      the permuted V layout: slot o<4 -> (k16=2c, r=o), o>=4 -> (2c+1) ----
    f16x8 pa[4];
#pragma unroll
    for (int c = 0; c < 4; ++c) {
      f16x8 h;
#pragma unroll
      for (int r = 0; r < 4; ++r) {
        h[r]     = (f16)(s[2 * c][r] * ej);
        h[r + 4] = (f16)(s[2 * c + 1][r] * ej);
      }
      pa[c] = h;
    }

    // ---- U <- e_i * U (U rows are lg*4+j; fetch those rows' e_i) ----
    const float eu0 = __shfl(ei, lg * 4 + 0);
    const float eu1 = __shfl(ei, lg * 4 + 1);
    const float eu2 = __shfl(ei, lg * 4 + 2);
    const float eu3 = __shfl(ei, lg * 4 + 3);
#pragma unroll
    for (int n = 0; n < 8; ++n) {
      u[n][0] *= eu0; u[n][1] *= eu1; u[n][2] *= eu2; u[n][3] *= eu3;
    }

    // ---- U += P V : B-frag = Vs[d = n*16+ll][slot = c*32 + lg*8 + o] ----
    const char* Vc = (const char*)&Vs[cur][0];
#pragma unroll
    for (int c = 0; c < 4; ++c) {
      const int boff = (c * 64 + lg * 16) ^ swz;
#pragma unroll
      for (int n = 0; n < 8; ++n) {
        f16x8 vf = *(const f16x8*)(Vc + (n * 16 + ll) * 256 + boff);
        u[n] = __builtin_amdgcn_mfma_f32_16x16x32_f16(pa[c], vf, u[n], 0, 0, 0);
      }
    }

    __syncthreads();   // drains stage vmcnt + all LDS reads: one barrier/iter
  }

  // ---- epilogue: O = U / l  (l for PV-row lg*4+j lives at lane lg*4+j) ----
  const float rl0 = 1.f / __shfl(lsum, lg * 4 + 0);
  const float rl1 = 1.f / __shfl(lsum, lg * 4 + 1);
  const float rl2 = 1.f / __shfl(lsum, lg * 4 + 2);
  const float rl3 = 1.f / __shfl(lsum, lg * 4 + 3);
  const size_t rbase = (size_t)(qt * 128 + w * 16 + lg * 4);
#pragma unroll
  for (int n = 0; n < 8; ++n) {
    const int col = n * 16 + ll;
    OB[(rbase + 0) * DK + col] = u[n][0] * rl0;
    OB[(rbase + 1) * DK + col] = u[n][1] * rl1;
    OB[(rbase + 2) * DK + col] = u[n][2] * rl2;
    OB[(rbase + 3) * DK + col] = u[n][3] * rl3;
  }
}

extern "C" void kernel_launch(void* const* d_in, const int* in_sizes, int n_in,
                              void* d_out, int out_size, void* d_ws, size_t ws_size,
                              hipStream_t stream) {
  const float* Q = (const float*)d_in[0];
  const float* K = (const float*)d_in[1];
  const float* V = (const float*)d_in[2];
  float* O = (float*)d_out;
  (void)in_sizes; (void)n_in; (void)out_size; (void)ws_size;

  f16* Kh  = (f16*)d_ws;                          // 16 MB
  f16* Vtp = (f16*)((char*)d_ws + 16777216);      // 16 MB (needs ws >= 32MB)

  cvt_k<<<4096, 256, 0, stream>>>(K, Kh);
  trans_v<<<dim3(16, 32), 256, 0, stream>>>(V, Vtp);
  fa_fwd_f16<<<dim3(32, 16), 512, 0, stream>>>(Q, Kh, Vtp, O);
}

// Round 4
// 192.325 us; speedup vs baseline: 8.2747x; 1.0119x over previous
//
#include <hip/hip_runtime.h>
#include <math.h>

// FlashAttention fwd, faithful to reference blockwise recurrence INCLUDING the
// e_ij = exp(m_ij - m_new) per-128-block bug. f16 MFMA 16x16x32, fp32 accum.
// (b,h,s,d) = (2,16,2048,128) fp32 in/out. B_C = 128 (semantic).
//
// R4: same main structure as R3 (swapped QK^T -> in-register softmax; permuted
// V^T so PV A-frags pack with zero cross-lane traffic; K/V double-buffered,
// one barrier/iter). Changes:
//  - fused prep_kv pre-pass with COALESCED Vtp stores (R3's trans_v was ~90us
//    due to 64-line scattered 16B stores; now 4x256B contiguous per instr)
//  - s_setprio(1) around MFMA clusters (T5)
//  - XCD-grouped block swizzle: xcd n&7 owns 4 bh's (1MB f16 K+V per bh ->
//    4 bh fit one 4MB XCD L2), longest-qt-first within each XCD stream.

using f16   = _Float16;
using f16x8 = __attribute__((ext_vector_type(8))) _Float16;
using f32x4 = __attribute__((ext_vector_type(4))) float;

#define SEQ 2048
#define DK  128
#define FA_SCALE 0.08838834764831843f   // 1/sqrt(128)

// ---- fused pre-pass: Kh = f16(K) same layout; Vtp = f16 permuted V^T ----
// Vtp[bh][d][blk*128 + slot], slot(r*8+o) -> phys k = 32*(r>>2) + 16*(o>>2)
// + 4*(r&3) + (o&3)  (bijective within the 128-key block).
__global__ __launch_bounds__(256) void prep_kv(const float* __restrict__ K,
                                               const float* __restrict__ V,
                                               f16* __restrict__ Kh,
                                               f16* __restrict__ Vtp) {
  __shared__ float Vsh[128][132];          // +4 pad
  const int st = blockIdx.x, bh = blockIdx.y, tid = threadIdx.x;
  const size_t blk = ((size_t)bh * SEQ + st * 128) * DK;

  // K convert: fully coalesced (32B reads, 16B writes per lane)
  const float* Ksrc = K + blk;
  f16* Kdst = Kh + blk;
#pragma unroll
  for (int i = 0; i < 8; ++i) {
    int u = tid + i * 256;                 // 2048 x 8-float units
    float4 a = *(const float4*)(Ksrc + u * 8);
    float4 b = *(const float4*)(Ksrc + u * 8 + 4);
    f16x8 h;
    h[0] = (f16)a.x; h[1] = (f16)a.y; h[2] = (f16)a.z; h[3] = (f16)a.w;
    h[4] = (f16)b.x; h[5] = (f16)b.y; h[6] = (f16)b.z; h[7] = (f16)b.w;
    *(f16x8*)(Kdst + u * 8) = h;
  }

  // V stage to LDS (coalesced float4 reads)
  const float* Vsrc = V + blk;
#pragma unroll
  for (int i = 0; i < 16; ++i) {
    int f = tid + i * 256;
    int k = f >> 5, c = f & 31;
    *(float4*)&Vsh[k][c * 4] = *(const float4*)(Vsrc + k * DK + c * 4);
  }
  __syncthreads();

  // gather (permuted k) + store: per wave-instr 4 d-rows x 256B contiguous
  const int l = tid & 63, wv = tid >> 6;
  const int r = l & 15, dr = l >> 4;
  f16* Vdst = Vtp + (size_t)bh * DK * SEQ + st * 128;
#pragma unroll
  for (int it = 0; it < 8; ++it) {
    int d = wv * 32 + it * 4 + dr;
    f16x8 h;
#pragma unroll
    for (int o = 0; o < 8; ++o) {
      int k = 32 * (r >> 2) + 16 * (o >> 2) + 4 * (r & 3) + (o & 3);
      h[o] = (f16)Vsh[k][d];
    }
    *(f16x8*)(Vdst + (size_t)d * SEQ + r * 8) = h;
  }
}

// ---------------- main kernel helpers ----------------
__device__ __forceinline__ void gl_lds16(const void* g, void* l) {
  __builtin_amdgcn_global_load_lds(
      (const __attribute__((address_space(1))) unsigned int*)g,
      (__attribute__((address_space(3))) unsigned int*)l, 16, 0, 0);
}

// Stage a 128-row x 256B tile (32 KB) into LDS; global source pre-swizzled so
// swizzled reads (byte ^ ((row&7)<<4)) see the logical layout. (Proven R2/R3.)
__device__ __forceinline__ void stage32k(const char* gbase, size_t gstride,
                                         char* lds, int w, int lg, int ll) {
#pragma unroll
  for (int i = 0; i < 4; ++i) {
    int t = w * 4 + i;                 // 32 x 1KB chunks, 4 per wave
    int row = t * 4 + lg;
    int blog = (ll * 16) ^ ((row & 7) << 4);
    gl_lds16(gbase + (size_t)row * gstride + blog, lds + t * 1024);
  }
}

__global__ __launch_bounds__(512, 2) void fa_fwd_f16(
    const float* __restrict__ Q, const f16* __restrict__ Kh,
    const f16* __restrict__ Vtp, float* __restrict__ O) {
  // XCD-grouped swizzle: xcd = n&7 owns bh in {4*xcd .. 4*xcd+3};
  // within an XCD stream, qt descends (longest tiles first).
  const int n = blockIdx.x;
  const int m = n >> 3;
  const int bh = (n & 7) * 4 + (m & 3);
  const int qt = 15 - (m >> 2);

  const int tid  = threadIdx.x;
  const int lane = tid & 63;
  const int w  = tid >> 6;                 // wave 0..7: owns q-rows w*16..+15
  const int ll = lane & 15;
  const int lg = lane >> 4;
  const int swz = (ll & 7) << 4;

  __shared__ __align__(16) f16 Ks[2][128 * 128];   // 2 x 32 KB
  __shared__ __align__(16) f16 Vs[2][128 * 128];   // 2 x 32 KB (permuted V^T)

  const float* QB = Q + (size_t)bh * SEQ * DK;
  const char*  KB = (const char*)(Kh + (size_t)bh * SEQ * DK);
  const char*  VB = (const char*)(Vtp + (size_t)bh * DK * SEQ);
  float*       OB = O + (size_t)bh * SEQ * DK;

  const int qrow = qt * 128 + w * 16 + ll;   // this lane's q-row (QK side)

  // Q B-frag (regs): B[q=ll][d = dc*32 + lg*8 + o]
  f16x8 qf[4];
#pragma unroll
  for (int dc = 0; dc < 4; ++dc) {
    const float* p = QB + (size_t)qrow * DK + dc * 32 + lg * 8;
    float4 a = *(const float4*)p, b = *(const float4*)(p + 4);
    f16x8 h;
    h[0] = (f16)a.x; h[1] = (f16)a.y; h[2] = (f16)a.z; h[3] = (f16)a.w;
    h[4] = (f16)b.x; h[5] = (f16)b.y; h[6] = (f16)b.z; h[7] = (f16)b.w;
    qf[dc] = h;
  }

  f32x4 u[8];                 // U: rows lg*4+j (within wave), cols n*16+ll
#pragma unroll
  for (int nn = 0; nn < 8; ++nn) u[nn] = 0;
  float m_run = -INFINITY, lsum = 0.f;   // per-lane q-row state

  stage32k(KB, 256, (char*)&Ks[0][0], w, lg, ll);
  stage32k(VB, 4096, (char*)&Vs[0][0], w, lg, ll);
  __syncthreads();

  for (int kb = 0; kb <= qt; ++kb) {
    const int cur = kb & 1;
    if (kb < qt) {   // prefetch next block (drained at this iter's end barrier)
      stage32k(KB + (size_t)(kb + 1) * 32768, 256, (char*)&Ks[cur ^ 1][0], w, lg, ll);
      stage32k(VB + (size_t)(kb + 1) * 256, 4096, (char*)&Vs[cur ^ 1][0], w, lg, ll);
    }

    // ---- S^T = K Q^T : s[k16][r] = S[q=ll][k = k16*16 + lg*4 + r] ----
    f32x4 s[8];
#pragma unroll
    for (int k16 = 0; k16 < 8; ++k16) s[k16] = 0;
    const char* Kc = (const char*)&Ks[cur][0];
    __builtin_amdgcn_s_setprio(1);
#pragma unroll
    for (int dc = 0; dc < 4; ++dc) {
      const int boff = (dc * 64 + lg * 16) ^ swz;
#pragma unroll
      for (int k16 = 0; k16 < 8; ++k16) {
        f16x8 kf = *(const f16x8*)(Kc + (k16 * 16 + ll) * 256 + boff);
        s[k16] = __builtin_amdgcn_mfma_f32_16x16x32_f16(kf, qf[dc], s[k16], 0, 0, 0);
      }
    }
    __builtin_amdgcn_s_setprio(0);

    // ---- scale + causal mask (diag only) + in-register row max ----
    float mx = -INFINITY;
    if (kb == qt) {
      const int kbase = kb * 128;
#pragma unroll
      for (int k16 = 0; k16 < 8; ++k16)
#pragma unroll
        for (int r = 0; r < 4; ++r) {
          float v = s[k16][r] * FA_SCALE;
          if (kbase + k16 * 16 + lg * 4 + r > qrow) v = -INFINITY;
          s[k16][r] = v;
          mx = fmaxf(mx, v);
        }
    } else {
#pragma unroll
      for (int k16 = 0; k16 < 8; ++k16)
#pragma unroll
        for (int r = 0; r < 4; ++r) {
          float v = s[k16][r] * FA_SCALE;
          s[k16][r] = v;
          mx = fmaxf(mx, v);
        }
    }
    mx = fmaxf(mx, __shfl_xor(mx, 16));   // combine the 4 lg copies of row ll
    mx = fmaxf(mx, __shfl_xor(mx, 32));

    const float mn = fmaxf(m_run, mx);    // m_new
    const float ei = __expf(m_run - mn);  // exp(-inf)=0 on first block
    const float ej = __expf(mx - mn);     // the reference's e_ij bug factor
    m_run = mn;

    // ---- P = exp(S - m_new); plain row sum for l ----
    float ps = 0.f;
#pragma unroll
    for (int k16 = 0; k16 < 8; ++k16)
#pragma unroll
      for (int r = 0; r < 4; ++r) {
        float p = __expf(s[k16][r] - mn);
        s[k16][r] = p;
        ps += p;
      }
    ps += __shfl_xor(ps, 16);
    ps += __shfl_xor(ps, 32);
    lsum = ei * lsum + ps;

    // ---- pack PV A-frags in-register (e_ij folded); matches permuted V ----
    f16x8 pa[4];
#pragma unroll
    for (int c = 0; c < 4; ++c) {
      f16x8 h;
#pragma unroll
      for (int r = 0; r < 4; ++r) {
        h[r]     = (f16)(s[2 * c][r] * ej);
        h[r + 4] = (f16)(s[2 * c + 1][r] * ej);
      }
      pa[c] = h;
    }

    // ---- U <- e_i * U (U rows are lg*4+j; fetch those rows' e_i) ----
    const float eu0 = __shfl(ei, lg * 4 + 0);
    const float eu1 = __shfl(ei, lg * 4 + 1);
    const float eu2 = __shfl(ei, lg * 4 + 2);
    const float eu3 = __shfl(ei, lg * 4 + 3);
#pragma unroll
    for (int nn = 0; nn < 8; ++nn) {
      u[nn][0] *= eu0; u[nn][1] *= eu1; u[nn][2] *= eu2; u[nn][3] *= eu3;
    }

    // ---- U += P V : B-frag = Vs[d = nn*16+ll][slot = c*32 + lg*8 + o] ----
    const char* Vc = (const char*)&Vs[cur][0];
    __builtin_amdgcn_s_setprio(1);
#pragma unroll
    for (int c = 0; c < 4; ++c) {
      const int boff = (c * 64 + lg * 16) ^ swz;
#pragma unroll
      for (int nn = 0; nn < 8; ++nn) {
        f16x8 vf = *(const f16x8*)(Vc + (nn * 16 + ll) * 256 + boff);
        u[nn] = __builtin_amdgcn_mfma_f32_16x16x32_f16(pa[c], vf, u[nn], 0, 0, 0);
      }
    }
    __builtin_amdgcn_s_setprio(0);

    __syncthreads();   // drains stage vmcnt + all LDS reads: one barrier/iter
  }

  // ---- epilogue: O = U / l  (l for PV-row lg*4+j lives at lane lg*4+j) ----
  const float rl0 = 1.f / __shfl(lsum, lg * 4 + 0);
  const float rl1 = 1.f / __shfl(lsum, lg * 4 + 1);
  const float rl2 = 1.f / __shfl(lsum, lg * 4 + 2);
  const float rl3 = 1.f / __shfl(lsum, lg * 4 + 3);
  const size_t rbase = (size_t)(qt * 128 + w * 16 + lg * 4);
#pragma unroll
  for (int nn = 0; nn < 8; ++nn) {
    const int col = nn * 16 + ll;
    OB[(rbase + 0) * DK + col] = u[nn][0] * rl0;
    OB[(rbase + 1) * DK + col] = u[nn][1] * rl1;
    OB[(rbase + 2) * DK + col] = u[nn][2] * rl2;
    OB[(rbase + 3) * DK + col] = u[nn][3] * rl3;
  }
}

extern "C" void kernel_launch(void* const* d_in, const int* in_sizes, int n_in,
                              void* d_out, int out_size, void* d_ws, size_t ws_size,
                              hipStream_t stream) {
  const float* Q = (const float*)d_in[0];
  const float* K = (const float*)d_in[1];
  const float* V = (const float*)d_in[2];
  float* O = (float*)d_out;
  (void)in_sizes; (void)n_in; (void)out_size; (void)ws_size;

  f16* Kh  = (f16*)d_ws;                          // 16 MB
  f16* Vtp = (f16*)((char*)d_ws + 16777216);      // 16 MB (needs ws >= 32MB)

  prep_kv<<<dim3(16, 32), 256, 0, stream>>>(K, V, Kh, Vtp);
  fa_fwd_f16<<<512, 512, 0, stream>>>(Q, Kh, Vtp, O);
}